// Round 2
// baseline (271.872 us; speedup 1.0000x reference)
//
#include <hip/hip_runtime.h>

typedef __bf16 bf16;
typedef __bf16 bf16x8 __attribute__((ext_vector_type(8)));
typedef __bf16 bf16x4 __attribute__((ext_vector_type(4)));
typedef float f32x4 __attribute__((ext_vector_type(4)));
typedef float fx2 __attribute__((ext_vector_type(2)));
typedef unsigned int u32x2 __attribute__((ext_vector_type(2)));

#define DEV static __device__ __forceinline__

constexpr int BB = 2, SS = 2048, DM = 1024, NH = 16, HD = 64;
constexpr int MTOT = BB * SS;  // 4096
constexpr float LOG2E = 1.4426950408889634f;

// ---- workspace layout (bytes) ----
constexpr size_t OFF_XB   = 0;                                  // bf16 [4096][1024]
constexpr size_t OFF_WQKV = OFF_XB   + (size_t)MTOT * DM * 2;   // bf16 [3072][1024]
constexpr size_t OFF_WO   = OFF_WQKV + (size_t)3 * DM * DM * 2; // bf16 [1024][1024]
constexpr size_t OFF_TAB  = OFF_WO   + (size_t)DM * DM * 2;     // fx2  [2048][32]
constexpr size_t OFF_Q    = OFF_TAB  + (size_t)SS * (HD/2) * 8; // bf16 (B,H,S,d)
constexpr size_t OFF_K    = OFF_Q    + (size_t)MTOT * DM * 2;
constexpr size_t OFF_VT   = OFF_K    + (size_t)MTOT * DM * 2;   // bf16 (B,H,d,S)
constexpr size_t OFF_AO   = OFF_VT   + (size_t)MTOT * DM * 2;   // bf16 [4096][1024]

typedef const __attribute__((address_space(1))) void gas_void;
typedef __attribute__((address_space(3))) void las_void;

DEV void gload16(const bf16* g, bf16* l) {
  __builtin_amdgcn_global_load_lds((gas_void*)g, (las_void*)l, 16, 0, 0);
}

DEV f32x4 mfma16(bf16x8 a, bf16x8 b, f32x4 c) {
  return __builtin_amdgcn_mfma_f32_16x16x32_bf16(a, b, c, 0, 0, 0);
}

DEV unsigned pack2(float a, float b) {
  union { bf16 h[2]; unsigned u; } cv;
  cv.h[0] = (bf16)a; cv.h[1] = (bf16)b;
  return cv.u;
}

DEV u32x2 tr_read(unsigned addr) {
  u32x2 r;
  asm volatile("ds_read_b64_tr_b16 %0, %1" : "=v"(r) : "v"(addr));
  return r;
}

DEV bf16x8 combine4(u32x2 r0, u32x2 r1) {
  union { unsigned u[4]; bf16x8 v; } cv;
  cv.u[0] = r0[0]; cv.u[1] = r0[1]; cv.u[2] = r1[0]; cv.u[3] = r1[1];
  return cv.v;
}

// ---------------- prep: fp32 -> bf16 casts + RoPE table ----------------
__global__ void prep_kernel(const float* __restrict__ x, const float* __restrict__ wq,
    const float* __restrict__ wk, const float* __restrict__ wv, const float* __restrict__ wo,
    const int* __restrict__ pos, bf16* __restrict__ xb, bf16* __restrict__ wqkv,
    bf16* __restrict__ wob, fx2* __restrict__ tab) {
  const int NX4 = MTOT * DM / 4;     // 1048576
  const int NW4 = DM * DM / 4;       // 262144 = 2^18
  const int TOTC = NX4 + 4 * NW4;    // 2097152
  const int NTAB = SS * (HD / 2);    // 65536
  const int total = TOTC + NTAB;
  for (int i = blockIdx.x * blockDim.x + threadIdx.x; i < total; i += gridDim.x * blockDim.x) {
    if (i < TOTC) {
      const float* src; bf16* dst; int off;
      if (i < NX4) { src = x; dst = xb; off = i; }
      else {
        int i2 = i - NX4; int which = i2 >> 18; off = i2 & (NW4 - 1);
        src = which == 0 ? wq : which == 1 ? wk : which == 2 ? wv : wo;
        dst = which == 0 ? wqkv : which == 1 ? wqkv + DM * DM : which == 2 ? wqkv + 2 * DM * DM : wob;
      }
      float4 v = ((const float4*)src)[off];
      bf16x4 o4 = { (bf16)v.x, (bf16)v.y, (bf16)v.z, (bf16)v.w };
      ((bf16x4*)dst)[off] = o4;
    } else {
      int e = i - TOTC;
      int s = e >> 5, p = e & 31;
      // inv_freq = 10000^(-p/32) = 2^(-p * log2(10000)/32)
      float invf = __builtin_exp2f(-(float)p * (13.287712379549449f / 32.0f));
      float ang = (float)pos[s] * invf;
      fx2 cs; cs.x = cosf(ang); cs.y = sinf(ang);
      tab[e] = cs;
    }
  }
}

// ---------------- 128x128 bf16 GEMM mainloop (C[m,n] = sum_k A[m,k]*B[n,k]) ----------------
DEV void gemm_bt_128(const bf16* __restrict__ A, const bf16* __restrict__ Bw,
                     int rowA0, int rowB0, f32x4 (&acc)[4][4]) {
  __shared__ __align__(16) bf16 lA[128 * 32];
  __shared__ __align__(16) bf16 lB[128 * 32];
  const int t = threadIdx.x, w = t >> 6, lane = t & 63;
  const int wr = w >> 1, wc = w & 1, g = lane >> 4, c = lane & 15;
#pragma unroll
  for (int mi = 0; mi < 4; mi++)
#pragma unroll
    for (int ni = 0; ni < 4; ni++) acc[mi][ni] = (f32x4){0.f, 0.f, 0.f, 0.f};
  const bf16* ga = A + (size_t)(rowA0 + (t >> 2)) * DM + (t & 3) * 8;
  const bf16* gb = Bw + (size_t)(rowB0 + (t >> 2)) * DM + (t & 3) * 8;
  bf16* la = lA + w * 512;   // wave-uniform LDS base (bytes: w*1024)
  bf16* lb = lB + w * 512;
  const int arow = wr * 64 + c, brow = wc * 64 + c;
  for (int k0 = 0; k0 < DM; k0 += 32) {
    gload16(ga + k0,            la);
    gload16(ga + k0 + 64 * DM,  la + 2048);
    gload16(gb + k0,            lb);
    gload16(gb + k0 + 64 * DM,  lb + 2048);
    __syncthreads();
    bf16x8 af[4], bf_[4];
#pragma unroll
    for (int mi = 0; mi < 4; mi++) af[mi]  = *(const bf16x8*)(lA + (arow + mi * 16) * 32 + g * 8);
#pragma unroll
    for (int ni = 0; ni < 4; ni++) bf_[ni] = *(const bf16x8*)(lB + (brow + ni * 16) * 32 + g * 8);
#pragma unroll
    for (int mi = 0; mi < 4; mi++)
#pragma unroll
      for (int ni = 0; ni < 4; ni++)
        acc[mi][ni] = mfma16(af[mi], bf_[ni], acc[mi][ni]);
    __syncthreads();
  }
}

// ---------------- QKV projection + RoPE epilogue ----------------
__global__ __launch_bounds__(256, 2) void qkv_kernel(const bf16* __restrict__ xb,
    const bf16* __restrict__ wqkv, const fx2* __restrict__ tab,
    bf16* __restrict__ Qb, bf16* __restrict__ Kb, bf16* __restrict__ VTb) {
  f32x4 acc[4][4];
  const int rowA0 = blockIdx.y * 128, rowB0 = blockIdx.x * 128;
  gemm_bt_128(xb, wqkv, rowA0, rowB0, acc);
  const int t = threadIdx.x, w = t >> 6, lane = t & 63;
  const int wr = w >> 1, wc = w & 1, g = lane >> 4, c = lane & 15;
  const int which = rowB0 >> 10;   // 0=q 1=k 2=v (uniform per block)
#pragma unroll
  for (int mi = 0; mi < 4; mi++)
#pragma unroll
    for (int ni = 0; ni < 4; ni++) {
      const int ncol = rowB0 + wc * 64 + ni * 16 + c;
      const int nn = ncol & (DM - 1), h = nn >> 6, dd = nn & 63;
#pragma unroll
      for (int j = 0; j < 4; j++) {
        const int mrow = rowA0 + wr * 64 + mi * 16 + 4 * g + j;
        const int b = mrow >> 11, s = mrow & (SS - 1);
        float v = acc[mi][ni][j];
        if (which < 2) {
          float partner = __shfl_xor(v, 1);
          fx2 cs = tab[s * 32 + (dd >> 1)];
          v = v * cs.x + ((dd & 1) ? partner : -partner) * cs.y;
          bf16* dst = which == 0 ? Qb : Kb;
          dst[((size_t)((b * NH + h) * SS + s)) * HD + dd] = (bf16)v;
        } else {
          VTb[((size_t)((b * NH + h) * HD + dd)) * SS + s] = (bf16)v;
        }
      }
    }
}

// ---------------- flash attention (causal), 4 waves x 32 q-rows ----------------
// P relay through LDS, per-wave 4KB region, per qf (16 q-rows) a 2KB sub-region
// laid out [k=0..63][q'=0..15] row-major bf16 (32B per k-row).
//   write: lane(g,c) holds P[q'=4g+j][k=kf*16+c] -> b64 at (kf*16+c)*32 + 8g
//   read:  tr_read tiles t=8*kc2+2g, t+1 at addr = region + 128*t + 8*c
//          -> lane(g,c) elems e=0..7 = P[q'=c][k=32*kc2+8g+e]   (PV A-frag)
__global__ __launch_bounds__(256, 2) void attn_kernel(const bf16* __restrict__ Q,
    const bf16* __restrict__ K, const bf16* __restrict__ VT, bf16* __restrict__ AO) {
  __shared__ __align__(16) unsigned char pmem[4][4096];
  const int bh = blockIdx.y;
  const int t = threadIdx.x, w = t >> 6, lane = t & 63, g = lane >> 4, c = lane & 15;
  const bf16* Qp = Q + (size_t)bh * SS * HD;
  const bf16* Kp = K + (size_t)bh * SS * HD;
  const bf16* Vp = VT + (size_t)bh * HD * SS;
  const int qw = blockIdx.x * 128 + w * 32;
  unsigned char* pb = &pmem[w][0];
  const unsigned lbase = (unsigned)(size_t)(__attribute__((address_space(3))) unsigned char*)pb;

  // Q fragments, pre-scaled by 1/sqrt(64)=0.125 (exact power of two)
  bf16x8 qa[2][2];
#pragma unroll
  for (int fr = 0; fr < 2; fr++)
#pragma unroll
    for (int kc = 0; kc < 2; kc++) {
      bf16x8 xq = *(const bf16x8*)(Qp + (qw + fr * 16 + c) * HD + kc * 32 + g * 8);
#pragma unroll
      for (int e = 0; e < 8; e++) xq[e] = (bf16)((float)xq[e] * 0.125f);
      qa[fr][kc] = xq;
    }

  float m_run[2][4], l_run[2][4];
  f32x4 o[2][4];
#pragma unroll
  for (int fr = 0; fr < 2; fr++)
#pragma unroll
    for (int j = 0; j < 4; j++) { m_run[fr][j] = -3.0e38f; l_run[fr][j] = 0.f; }
#pragma unroll
  for (int fr = 0; fr < 2; fr++)
#pragma unroll
    for (int df = 0; df < 4; df++) o[fr][df] = (f32x4){0.f, 0.f, 0.f, 0.f};

  const int ntiles = (qw + 95) >> 6;
  for (int tv = 0; tv < ntiles; ++tv) {
    const int k0 = tv * 64;
    // ---- S = (Q*0.125) @ K^T over this 64-key tile ----
    f32x4 sc[2][4];
#pragma unroll
    for (int kf = 0; kf < 4; kf++) {
      const bf16* kr = Kp + (k0 + kf * 16 + c) * HD + g * 8;
      bf16x8 kb0 = *(const bf16x8*)(kr);
      bf16x8 kb1 = *(const bf16x8*)(kr + 32);
#pragma unroll
      for (int fr = 0; fr < 2; fr++) {
        f32x4 z = (f32x4){0.f, 0.f, 0.f, 0.f};
        z = mfma16(qa[fr][0], kb0, z);
        z = mfma16(qa[fr][1], kb1, z);
        sc[fr][kf] = z;
      }
    }
    // ---- causal mask (only diagonal-overlapping tiles) ----
    if (k0 + 63 > qw) {
#pragma unroll
      for (int fr = 0; fr < 2; fr++)
#pragma unroll
        for (int kf = 0; kf < 4; kf++) {
          const int kg = k0 + kf * 16 + c;
#pragma unroll
          for (int j = 0; j < 4; j++) {
            const int qg = qw + fr * 16 + 4 * g + j;
            if (kg > qg) sc[fr][kf][j] = -1.0e30f;
          }
        }
    }
    // ---- online softmax + write P into wave-private LDS ([k][q'] layout) ----
#pragma unroll
    for (int fr = 0; fr < 2; fr++) {
      float al[4];
#pragma unroll
      for (int j = 0; j < 4; j++) {
        float mx = fmaxf(fmaxf(sc[fr][0][j], sc[fr][1][j]), fmaxf(sc[fr][2][j], sc[fr][3][j]));
        mx = fmaxf(mx, __shfl_xor(mx, 1));
        mx = fmaxf(mx, __shfl_xor(mx, 2));
        mx = fmaxf(mx, __shfl_xor(mx, 4));
        mx = fmaxf(mx, __shfl_xor(mx, 8));
        const float mold = m_run[fr][j];
        const float mnew = fmaxf(mold, mx);
        const float alpha = __builtin_exp2f((mold - mnew) * LOG2E);
        float rs = 0.f;
#pragma unroll
        for (int kf = 0; kf < 4; kf++) {
          float p = __builtin_exp2f((sc[fr][kf][j] - mnew) * LOG2E);
          sc[fr][kf][j] = p; rs += p;
        }
        rs += __shfl_xor(rs, 1);
        rs += __shfl_xor(rs, 2);
        rs += __shfl_xor(rs, 4);
        rs += __shfl_xor(rs, 8);
        l_run[fr][j] = alpha * l_run[fr][j] + rs;
        m_run[fr][j] = mnew;
        al[j] = alpha;
      }
#pragma unroll
      for (int df = 0; df < 4; df++)
#pragma unroll
        for (int j = 0; j < 4; j++) o[fr][df][j] *= al[j];
      // write P^T region: [k][q'] rows of 32B; lane(g,c) -> k=kf*16+c, q'=4g..4g+3
#pragma unroll
      for (int kf = 0; kf < 4; kf++) {
        u32x2 pk;
        pk[0] = pack2(sc[fr][kf][0], sc[fr][kf][1]);
        pk[1] = pack2(sc[fr][kf][2], sc[fr][kf][3]);
        const unsigned a = (unsigned)(fr * 2048 + (kf * 16 + c) * 32 + 8 * g);
        *(u32x2*)(pb + a) = pk;
      }
    }
    // ---- read P back as PV A-fragments via hardware transpose reads ----
    asm volatile("s_waitcnt lgkmcnt(0)" ::: "memory");
    bf16x8 pa[2][2];
#pragma unroll
    for (int qf = 0; qf < 2; qf++)
#pragma unroll
      for (int kc2 = 0; kc2 < 2; kc2++) {
        const unsigned base = lbase + qf * 2048 + 128u * (8 * kc2 + 2 * g) + 8 * c;
        u32x2 r0 = tr_read(base);
        u32x2 r1 = tr_read(base + 128);
        pa[qf][kc2] = combine4(r0, r1);
      }
    asm volatile("s_waitcnt lgkmcnt(0)" ::: "memory");
    __builtin_amdgcn_sched_barrier(0);
    // ---- O += P @ V  (V^T rows are contiguous in k) ----
#pragma unroll
    for (int df = 0; df < 4; df++) {
      const bf16* vr = Vp + (df * 16 + c) * SS + k0 + g * 8;
      bf16x8 vb0 = *(const bf16x8*)(vr);
      bf16x8 vb1 = *(const bf16x8*)(vr + 32);
#pragma unroll
      for (int qf = 0; qf < 2; qf++) {
        o[qf][df] = mfma16(pa[qf][0], vb0, o[qf][df]);
        o[qf][df] = mfma16(pa[qf][1], vb1, o[qf][df]);
      }
    }
  }
  // ---- epilogue: normalize and store (B*S, D) bf16 ----
  const int b = bh >> 4, h = bh & 15;
#pragma unroll
  for (int qf = 0; qf < 2; qf++) {
    float inv[4];
#pragma unroll
    for (int j = 0; j < 4; j++) inv[j] = 1.0f / l_run[qf][j];
#pragma unroll
    for (int df = 0; df < 4; df++)
#pragma unroll
      for (int j = 0; j < 4; j++) {
        const int row = b * SS + qw + qf * 16 + 4 * g + j;
        const int col = h * HD + df * 16 + c;
        AO[(size_t)row * DM + col] = (bf16)(o[qf][df][j] * inv[j]);
      }
  }
}

// ---------------- output projection -> fp32 d_out ----------------
__global__ __launch_bounds__(256, 2) void oproj_kernel(const bf16* __restrict__ AO,
    const bf16* __restrict__ wob, float* __restrict__ out) {
  f32x4 acc[4][4];
  const int rowA0 = blockIdx.y * 128, rowB0 = blockIdx.x * 128;
  gemm_bt_128(AO, wob, rowA0, rowB0, acc);
  const int t = threadIdx.x, w = t >> 6, lane = t & 63;
  const int wr = w >> 1, wc = w & 1, g = lane >> 4, c = lane & 15;
#pragma unroll
  for (int mi = 0; mi < 4; mi++)
#pragma unroll
    for (int ni = 0; ni < 4; ni++) {
      const int ncol = rowB0 + wc * 64 + ni * 16 + c;
#pragma unroll
      for (int j = 0; j < 4; j++) {
        const int mrow = rowA0 + wr * 64 + mi * 16 + 4 * g + j;
        out[(size_t)mrow * DM + ncol] = acc[mi][ni][j];
      }
    }
}

extern "C" void kernel_launch(void* const* d_in, const int* in_sizes, int n_in,
                              void* d_out, int out_size, void* d_ws, size_t ws_size,
                              hipStream_t stream) {
  const float* x  = (const float*)d_in[0];
  const float* wq = (const float*)d_in[1];
  const float* wk = (const float*)d_in[2];
  const float* wv = (const float*)d_in[3];
  const float* wo = (const float*)d_in[4];
  const int*   pos = (const int*)d_in[5];
  char* ws = (char*)d_ws;
  bf16* xb   = (bf16*)(ws + OFF_XB);
  bf16* wqkv = (bf16*)(ws + OFF_WQKV);
  bf16* wob  = (bf16*)(ws + OFF_WO);
  fx2*  tab  = (fx2*)(ws + OFF_TAB);
  bf16* Qb   = (bf16*)(ws + OFF_Q);
  bf16* Kb   = (bf16*)(ws + OFF_K);
  bf16* VTb  = (bf16*)(ws + OFF_VT);
  bf16* AOb  = (bf16*)(ws + OFF_AO);

  hipLaunchKernelGGL(prep_kernel, dim3(2048), dim3(256), 0, stream,
                     x, wq, wk, wv, wo, pos, xb, wqkv, wob, tab);
  hipLaunchKernelGGL(qkv_kernel, dim3(24, 32), dim3(256), 0, stream,
                     xb, wqkv, tab, Qb, Kb, VTb);
  hipLaunchKernelGGL(attn_kernel, dim3(16, 32), dim3(256), 0, stream,
                     Qb, Kb, VTb, AOb);
  hipLaunchKernelGGL(oproj_kernel, dim3(8, 32), dim3(256), 0, stream,
                     AOb, wob, (float*)d_out);
}

// Round 3
// 209.014 us; speedup vs baseline: 1.3007x; 1.3007x over previous
//
#include <hip/hip_runtime.h>

typedef __bf16 bf16;
typedef __bf16 bf16x8 __attribute__((ext_vector_type(8)));
typedef __bf16 bf16x4 __attribute__((ext_vector_type(4)));
typedef float f32x4 __attribute__((ext_vector_type(4)));
typedef float fx2 __attribute__((ext_vector_type(2)));
typedef unsigned int u32x2 __attribute__((ext_vector_type(2)));

#define DEV static __device__ __forceinline__

constexpr int BB = 2, SS = 2048, DM = 1024, NH = 16, HD = 64;
constexpr int MTOT = BB * SS;  // 4096
constexpr float LOG2E = 1.4426950408889634f;

// ---- workspace layout (bytes) ----
constexpr size_t OFF_XB   = 0;                                  // bf16 [4096][1024]
constexpr size_t OFF_WQKV = OFF_XB   + (size_t)MTOT * DM * 2;   // bf16 [3072][1024]
constexpr size_t OFF_WO   = OFF_WQKV + (size_t)3 * DM * DM * 2; // bf16 [1024][1024]
constexpr size_t OFF_TAB  = OFF_WO   + (size_t)DM * DM * 2;     // fx2  [2048][32]
constexpr size_t OFF_Q    = OFF_TAB  + (size_t)SS * (HD/2) * 8; // bf16 (B,H,S,d)
constexpr size_t OFF_K    = OFF_Q    + (size_t)MTOT * DM * 2;
constexpr size_t OFF_VT   = OFF_K    + (size_t)MTOT * DM * 2;   // bf16 (B,H,d,S)
constexpr size_t OFF_AO   = OFF_VT   + (size_t)MTOT * DM * 2;   // bf16 [4096][1024]

typedef const __attribute__((address_space(1))) void gas_void;
typedef __attribute__((address_space(3))) void las_void;

DEV void gload16(const bf16* g, bf16* l) {
  __builtin_amdgcn_global_load_lds((gas_void*)g, (las_void*)l, 16, 0, 0);
}

DEV f32x4 mfma16(bf16x8 a, bf16x8 b, f32x4 c) {
  return __builtin_amdgcn_mfma_f32_16x16x32_bf16(a, b, c, 0, 0, 0);
}

DEV unsigned pack2(float a, float b) {
  union { bf16 h[2]; unsigned u; } cv;
  cv.h[0] = (bf16)a; cv.h[1] = (bf16)b;
  return cv.u;
}

DEV u32x2 tr_read(unsigned addr) {
  u32x2 r;
  asm volatile("ds_read_b64_tr_b16 %0, %1" : "=v"(r) : "v"(addr));
  return r;
}

DEV bf16x8 combine4(u32x2 r0, u32x2 r1) {
  union { unsigned u[4]; bf16x8 v; } cv;
  cv.u[0] = r0[0]; cv.u[1] = r0[1]; cv.u[2] = r1[0]; cv.u[3] = r1[1];
  return cv.v;
}

// ---------------- prep: fp32 -> bf16 casts + RoPE table ----------------
__global__ void prep_kernel(const float* __restrict__ x, const float* __restrict__ wq,
    const float* __restrict__ wk, const float* __restrict__ wv, const float* __restrict__ wo,
    const int* __restrict__ pos, bf16* __restrict__ xb, bf16* __restrict__ wqkv,
    bf16* __restrict__ wob, fx2* __restrict__ tab) {
  const int NX4 = MTOT * DM / 4;     // 1048576
  const int NW4 = DM * DM / 4;       // 262144 = 2^18
  const int TOTC = NX4 + 4 * NW4;    // 2097152
  const int NTAB = SS * (HD / 2);    // 65536
  const int total = TOTC + NTAB;
  for (int i = blockIdx.x * blockDim.x + threadIdx.x; i < total; i += gridDim.x * blockDim.x) {
    if (i < TOTC) {
      const float* src; bf16* dst; int off;
      if (i < NX4) { src = x; dst = xb; off = i; }
      else {
        int i2 = i - NX4; int which = i2 >> 18; off = i2 & (NW4 - 1);
        src = which == 0 ? wq : which == 1 ? wk : which == 2 ? wv : wo;
        dst = which == 0 ? wqkv : which == 1 ? wqkv + DM * DM : which == 2 ? wqkv + 2 * DM * DM : wob;
      }
      float4 v = ((const float4*)src)[off];
      bf16x4 o4 = { (bf16)v.x, (bf16)v.y, (bf16)v.z, (bf16)v.w };
      ((bf16x4*)dst)[off] = o4;
    } else {
      int e = i - TOTC;
      int s = e >> 5, p = e & 31;
      float invf = __builtin_exp2f(-(float)p * (13.287712379549449f / 32.0f));
      float ang = (float)pos[s] * invf;
      fx2 cs; cs.x = cosf(ang); cs.y = sinf(ang);
      tab[e] = cs;
    }
  }
}

// ---------------- 128x128 bf16 GEMM mainloop (C[m,n] = sum_k A[m,k]*B[n,k]) ----------------
DEV void gemm_bt_128(const bf16* __restrict__ A, const bf16* __restrict__ Bw,
                     int rowA0, int rowB0, f32x4 (&acc)[4][4]) {
  __shared__ __align__(16) bf16 lA[128 * 32];
  __shared__ __align__(16) bf16 lB[128 * 32];
  const int t = threadIdx.x, w = t >> 6, lane = t & 63;
  const int wr = w >> 1, wc = w & 1, g = lane >> 4, c = lane & 15;
#pragma unroll
  for (int mi = 0; mi < 4; mi++)
#pragma unroll
    for (int ni = 0; ni < 4; ni++) acc[mi][ni] = (f32x4){0.f, 0.f, 0.f, 0.f};
  const bf16* ga = A + (size_t)(rowA0 + (t >> 2)) * DM + (t & 3) * 8;
  const bf16* gb = Bw + (size_t)(rowB0 + (t >> 2)) * DM + (t & 3) * 8;
  bf16* la = lA + w * 512;
  bf16* lb = lB + w * 512;
  const int arow = wr * 64 + c, brow = wc * 64 + c;
  for (int k0 = 0; k0 < DM; k0 += 32) {
    gload16(ga + k0,            la);
    gload16(ga + k0 + 64 * DM,  la + 2048);
    gload16(gb + k0,            lb);
    gload16(gb + k0 + 64 * DM,  lb + 2048);
    __syncthreads();
    bf16x8 af[4], bf_[4];
#pragma unroll
    for (int mi = 0; mi < 4; mi++) af[mi]  = *(const bf16x8*)(lA + (arow + mi * 16) * 32 + g * 8);
#pragma unroll
    for (int ni = 0; ni < 4; ni++) bf_[ni] = *(const bf16x8*)(lB + (brow + ni * 16) * 32 + g * 8);
#pragma unroll
    for (int mi = 0; mi < 4; mi++)
#pragma unroll
      for (int ni = 0; ni < 4; ni++)
        acc[mi][ni] = mfma16(af[mi], bf_[ni], acc[mi][ni]);
    __syncthreads();
  }
}

// ---------------- QKV projection + RoPE epilogue ----------------
__global__ __launch_bounds__(256, 2) void qkv_kernel(const bf16* __restrict__ xb,
    const bf16* __restrict__ wqkv, const fx2* __restrict__ tab,
    bf16* __restrict__ Qb, bf16* __restrict__ Kb, bf16* __restrict__ VTb) {
  f32x4 acc[4][4];
  const int rowA0 = blockIdx.y * 128, rowB0 = blockIdx.x * 128;
  gemm_bt_128(xb, wqkv, rowA0, rowB0, acc);
  const int t = threadIdx.x, w = t >> 6, lane = t & 63;
  const int wr = w >> 1, wc = w & 1, g = lane >> 4, c = lane & 15;
  const int which = rowB0 >> 10;
#pragma unroll
  for (int mi = 0; mi < 4; mi++)
#pragma unroll
    for (int ni = 0; ni < 4; ni++) {
      const int ncol = rowB0 + wc * 64 + ni * 16 + c;
      const int nn = ncol & (DM - 1), h = nn >> 6, dd = nn & 63;
#pragma unroll
      for (int j = 0; j < 4; j++) {
        const int mrow = rowA0 + wr * 64 + mi * 16 + 4 * g + j;
        const int b = mrow >> 11, s = mrow & (SS - 1);
        float v = acc[mi][ni][j];
        if (which < 2) {
          float partner = __shfl_xor(v, 1);
          fx2 cs = tab[s * 32 + (dd >> 1)];
          v = v * cs.x + ((dd & 1) ? partner : -partner) * cs.y;
          bf16* dst = which == 0 ? Qb : Kb;
          dst[((size_t)((b * NH + h) * SS + s)) * HD + dd] = (bf16)v;
        } else {
          VTb[((size_t)((b * NH + h) * HD + dd)) * SS + s] = (bf16)v;
        }
      }
    }
}

// ---------------- flash attention (causal), 1 wave/block, paired low/high chunks ----------------
// Wave pi handles q-rows [16*pi, 16*pi+16) (lo) and [2032-16*pi, 2048-16*pi) (hi).
// kmax_lo + kmax_hi = const -> uniform work across all 2048 waves.
// P relay per fr: 2KB region [k=0..63][q'=0..15] row-major bf16 (validated layout).
__global__ __launch_bounds__(64, 2) void attn_kernel(const bf16* __restrict__ Q,
    const bf16* __restrict__ K, const bf16* __restrict__ VT, bf16* __restrict__ AO) {
  __shared__ __align__(16) unsigned char pmem[2][2048];
  const int bh = blockIdx.y;
  const int pi = blockIdx.x;                 // 0..63
  const int lane = threadIdx.x & 63, g = lane >> 4, c = lane & 15;
  const bf16* Qp = Q + (size_t)bh * SS * HD;
  const bf16* Kp = K + (size_t)bh * SS * HD;
  const bf16* Vp = VT + (size_t)bh * HD * SS;
  const int ql = pi * 16;                    // low chunk base
  const int qh = 2032 - pi * 16;             // high chunk base
  const int kmax_lo = ql + 16;
  unsigned char* pb = &pmem[0][0];
  const unsigned lbase = (unsigned)(size_t)(__attribute__((address_space(3))) unsigned char*)pb;

  // Q fragments (A row = c), pre-scaled by 1/sqrt(64)=0.125
  bf16x8 qa_lo[2], qa_hi[2];
#pragma unroll
  for (int kc = 0; kc < 2; kc++) {
    bf16x8 xl = *(const bf16x8*)(Qp + (ql + c) * HD + kc * 32 + g * 8);
    bf16x8 xh = *(const bf16x8*)(Qp + (qh + c) * HD + kc * 32 + g * 8);
#pragma unroll
    for (int e = 0; e < 8; e++) {
      xl[e] = (bf16)((float)xl[e] * 0.125f);
      xh[e] = (bf16)((float)xh[e] * 0.125f);
    }
    qa_lo[kc] = xl; qa_hi[kc] = xh;
  }

  float m_lo[4], l_lo[4], m_hi[4], l_hi[4];
  f32x4 o_lo[4], o_hi[4];
#pragma unroll
  for (int j = 0; j < 4; j++) {
    m_lo[j] = -3.0e38f; l_lo[j] = 0.f; m_hi[j] = -3.0e38f; l_hi[j] = 0.f;
  }
#pragma unroll
  for (int df = 0; df < 4; df++) {
    o_lo[df] = (f32x4){0.f, 0.f, 0.f, 0.f};
    o_hi[df] = (f32x4){0.f, 0.f, 0.f, 0.f};
  }

  // online softmax + P relay for one 16-row chunk
  auto sm_relay = [&](f32x4 (&sc)[4], float (&mr)[4], float (&lr)[4], f32x4 (&oo)[4], int region) {
    float al[4];
#pragma unroll
    for (int j = 0; j < 4; j++) {
      float mx = fmaxf(fmaxf(sc[0][j], sc[1][j]), fmaxf(sc[2][j], sc[3][j]));
      mx = fmaxf(mx, __shfl_xor(mx, 1));
      mx = fmaxf(mx, __shfl_xor(mx, 2));
      mx = fmaxf(mx, __shfl_xor(mx, 4));
      mx = fmaxf(mx, __shfl_xor(mx, 8));
      const float mold = mr[j];
      const float mnew = fmaxf(mold, mx);
      const float alpha = __builtin_exp2f((mold - mnew) * LOG2E);
      float rs = 0.f;
#pragma unroll
      for (int kf = 0; kf < 4; kf++) {
        float p = __builtin_exp2f((sc[kf][j] - mnew) * LOG2E);
        sc[kf][j] = p; rs += p;
      }
      rs += __shfl_xor(rs, 1);
      rs += __shfl_xor(rs, 2);
      rs += __shfl_xor(rs, 4);
      rs += __shfl_xor(rs, 8);
      lr[j] = alpha * lr[j] + rs;
      mr[j] = mnew;
      al[j] = alpha;
    }
#pragma unroll
    for (int df = 0; df < 4; df++)
#pragma unroll
      for (int j = 0; j < 4; j++) oo[df][j] *= al[j];
#pragma unroll
    for (int kf = 0; kf < 4; kf++) {
      u32x2 pk;
      pk[0] = pack2(sc[kf][0], sc[kf][1]);
      pk[1] = pack2(sc[kf][2], sc[kf][3]);
      const unsigned a = (unsigned)(region * 2048 + (kf * 16 + c) * 32 + 8 * g);
      *(u32x2*)(pb + a) = pk;
    }
  };

  const int nt = (qh + 79) >> 6;   // ceil((qh+16)/64)
  for (int tv = 0; tv < nt; ++tv) {
    const int k0 = tv * 64;
    const bool lo_act = (k0 < kmax_lo);
    // ---- QK^T for this 64-key tile (K loads shared by both chunks) ----
    f32x4 sc_hi[4], sc_lo[4];
#pragma unroll
    for (int kf = 0; kf < 4; kf++) {
      const bf16* kr = Kp + (k0 + kf * 16 + c) * HD + g * 8;
      bf16x8 kb0 = *(const bf16x8*)(kr);
      bf16x8 kb1 = *(const bf16x8*)(kr + 32);
      f32x4 z = (f32x4){0.f, 0.f, 0.f, 0.f};
      z = mfma16(qa_hi[0], kb0, z);
      z = mfma16(qa_hi[1], kb1, z);
      sc_hi[kf] = z;
      if (lo_act) {
        f32x4 y = (f32x4){0.f, 0.f, 0.f, 0.f};
        y = mfma16(qa_lo[0], kb0, y);
        y = mfma16(qa_lo[1], kb1, y);
        sc_lo[kf] = y;
      }
    }
    // ---- V prefetch (hides under softmax) ----
    bf16x8 vb[4][2];
#pragma unroll
    for (int df = 0; df < 4; df++) {
      const bf16* vr = Vp + (df * 16 + c) * SS + k0 + g * 8;
      vb[df][0] = *(const bf16x8*)(vr);
      vb[df][1] = *(const bf16x8*)(vr + 32);
    }
    // ---- causal masks (diagonal tiles only) ----
    if (k0 + 63 > qh) {
#pragma unroll
      for (int kf = 0; kf < 4; kf++) {
        const int kg = k0 + kf * 16 + c;
#pragma unroll
        for (int j = 0; j < 4; j++)
          if (kg > qh + 4 * g + j) sc_hi[kf][j] = -1.0e30f;
      }
    }
    if (lo_act && (k0 + 63 > ql)) {
#pragma unroll
      for (int kf = 0; kf < 4; kf++) {
        const int kg = k0 + kf * 16 + c;
#pragma unroll
        for (int j = 0; j < 4; j++)
          if (kg > ql + 4 * g + j) sc_lo[kf][j] = -1.0e30f;
      }
    }
    // ---- softmax + relay ----
    sm_relay(sc_hi, m_hi, l_hi, o_hi, 1);
    if (lo_act) sm_relay(sc_lo, m_lo, l_lo, o_lo, 0);
    // ---- tr-read P back as PV A-fragments ----
    asm volatile("s_waitcnt lgkmcnt(0)" ::: "memory");
    bf16x8 pa_hi[2], pa_lo[2];
#pragma unroll
    for (int kc2 = 0; kc2 < 2; kc2++) {
      const unsigned base = lbase + 2048u + 128u * (8 * kc2 + 2 * g) + 8 * c;
      u32x2 r0 = tr_read(base);
      u32x2 r1 = tr_read(base + 128);
      pa_hi[kc2] = combine4(r0, r1);
    }
    if (lo_act) {
#pragma unroll
      for (int kc2 = 0; kc2 < 2; kc2++) {
        const unsigned base = lbase + 128u * (8 * kc2 + 2 * g) + 8 * c;
        u32x2 r0 = tr_read(base);
        u32x2 r1 = tr_read(base + 128);
        pa_lo[kc2] = combine4(r0, r1);
      }
    }
    asm volatile("s_waitcnt lgkmcnt(0)" ::: "memory");
    __builtin_amdgcn_sched_barrier(0);
    // ---- O += P @ V ----
#pragma unroll
    for (int df = 0; df < 4; df++) {
      o_hi[df] = mfma16(pa_hi[0], vb[df][0], o_hi[df]);
      o_hi[df] = mfma16(pa_hi[1], vb[df][1], o_hi[df]);
    }
    if (lo_act) {
#pragma unroll
      for (int df = 0; df < 4; df++) {
        o_lo[df] = mfma16(pa_lo[0], vb[df][0], o_lo[df]);
        o_lo[df] = mfma16(pa_lo[1], vb[df][1], o_lo[df]);
      }
    }
  }
  // ---- epilogue: normalize and store both chunks ----
  const int b = bh >> 4, h = bh & 15;
  auto store_chunk = [&](f32x4 (&oo)[4], float (&lr)[4], int qbase) {
    float inv[4];
#pragma unroll
    for (int j = 0; j < 4; j++) inv[j] = 1.0f / lr[j];
#pragma unroll
    for (int df = 0; df < 4; df++)
#pragma unroll
      for (int j = 0; j < 4; j++) {
        const int row = b * SS + qbase + 4 * g + j;
        const int col = h * HD + df * 16 + c;
        AO[(size_t)row * DM + col] = (bf16)(oo[df][j] * inv[j]);
      }
  };
  store_chunk(o_hi, l_hi, qh);
  store_chunk(o_lo, l_lo, ql);
}

// ---------------- output projection -> fp32 d_out ----------------
__global__ __launch_bounds__(256, 2) void oproj_kernel(const bf16* __restrict__ AO,
    const bf16* __restrict__ wob, float* __restrict__ out) {
  f32x4 acc[4][4];
  const int rowA0 = blockIdx.y * 128, rowB0 = blockIdx.x * 128;
  gemm_bt_128(AO, wob, rowA0, rowB0, acc);
  const int t = threadIdx.x, w = t >> 6, lane = t & 63;
  const int wr = w >> 1, wc = w & 1, g = lane >> 4, c = lane & 15;
#pragma unroll
  for (int mi = 0; mi < 4; mi++)
#pragma unroll
    for (int ni = 0; ni < 4; ni++) {
      const int ncol = rowB0 + wc * 64 + ni * 16 + c;
#pragma unroll
      for (int j = 0; j < 4; j++) {
        const int mrow = rowA0 + wr * 64 + mi * 16 + 4 * g + j;
        out[(size_t)mrow * DM + ncol] = acc[mi][ni][j];
      }
    }
}

extern "C" void kernel_launch(void* const* d_in, const int* in_sizes, int n_in,
                              void* d_out, int out_size, void* d_ws, size_t ws_size,
                              hipStream_t stream) {
  const float* x  = (const float*)d_in[0];
  const float* wq = (const float*)d_in[1];
  const float* wk = (const float*)d_in[2];
  const float* wv = (const float*)d_in[3];
  const float* wo = (const float*)d_in[4];
  const int*   pos = (const int*)d_in[5];
  char* ws = (char*)d_ws;
  bf16* xb   = (bf16*)(ws + OFF_XB);
  bf16* wqkv = (bf16*)(ws + OFF_WQKV);
  bf16* wob  = (bf16*)(ws + OFF_WO);
  fx2*  tab  = (fx2*)(ws + OFF_TAB);
  bf16* Qb   = (bf16*)(ws + OFF_Q);
  bf16* Kb   = (bf16*)(ws + OFF_K);
  bf16* VTb  = (bf16*)(ws + OFF_VT);
  bf16* AOb  = (bf16*)(ws + OFF_AO);

  hipLaunchKernelGGL(prep_kernel, dim3(2048), dim3(256), 0, stream,
                     x, wq, wk, wv, wo, pos, xb, wqkv, wob, tab);
  hipLaunchKernelGGL(qkv_kernel, dim3(24, 32), dim3(256), 0, stream,
                     xb, wqkv, tab, Qb, Kb, VTb);
  hipLaunchKernelGGL(attn_kernel, dim3(64, 32), dim3(64), 0, stream,
                     Qb, Kb, VTb, AOb);
  hipLaunchKernelGGL(oproj_kernel, dim3(8, 32), dim3(256), 0, stream,
                     AOb, wob, (float*)d_out);
}